// Round 1
// baseline (868.623 us; speedup 1.0000x reference)
//
#include <hip/hip_runtime.h>

// LiZAttention: gated delta-rule linear attention + causal softmax attention,
// shared QKV / output projections. B=2, N=2048, D=2048, H=16, KVH=4, HD=128.
// All matmuls via v_mfma_f32_16x16x32_bf16 (fp32 accumulate).

typedef unsigned short u16;
typedef short bf16x8 __attribute__((ext_vector_type(8)));
typedef float f32x4 __attribute__((ext_vector_type(4)));

#define DEV static __device__ __forceinline__

DEV f32x4 mfma(bf16x8 a, bf16x8 b, f32x4 c) {
  return __builtin_amdgcn_mfma_f32_16x16x32_bf16(a, b, c, 0, 0, 0);
}
DEV u16 f2b(float f) {
  unsigned int u = __builtin_bit_cast(unsigned int, f);
  u = (u + 0x7FFF + ((u >> 16) & 1)) >> 16;
  return (u16)u;
}
DEV float b2f(u16 b) {
  unsigned int u = ((unsigned int)b) << 16;
  return __builtin_bit_cast(float, u);
}
DEV float logsig(float x) { return fminf(x, 0.f) - log1pf(__expf(-fabsf(x))); }

// ---------------- conversion / packing ----------------
// hsb  = bf16(hs)                      [4096][2048]
// wqkvT[n][k] = bf16([wq|wk|wv][k][n]) [3072][2048]
// woT  [n][k] = bf16(wo[k][n])         [2048][2048]
__global__ __launch_bounds__(256) void k_conv(const float* __restrict__ hs,
    const float* __restrict__ wq, const float* __restrict__ wk,
    const float* __restrict__ wv, const float* __restrict__ wo,
    u16* __restrict__ hsb, u16* __restrict__ wqkvT, u16* __restrict__ woT) {
  long i = (long)blockIdx.x * 256 + threadIdx.x;
  const long NH = 8388608, NW = 6291456, NO = 4194304;
  if (i < NH) { hsb[i] = f2b(hs[i]); return; }
  i -= NH;
  if (i < NW) {
    long n = i >> 11, kk = i & 2047;
    float v = (n < 2048) ? wq[kk * 2048 + n]
            : (n < 2560) ? wk[kk * 512 + (n - 2048)]
                         : wv[kk * 512 + (n - 2560)];
    wqkvT[i] = f2b(v);
    return;
  }
  i -= NW;
  if (i < NO) {
    long n = i >> 11, kk = i & 2047;
    woT[i] = f2b(wo[kk * 2048 + n]);
  }
}

// ---------------- generic GEMM: C[M][N] = A[M][K] * Bt[N][K]^T ----------------
template <int OUT_F32>
__global__ __launch_bounds__(256) void k_gemm(const u16* __restrict__ A,
    const u16* __restrict__ Bt, void* __restrict__ Cout, int M, int N, int K) {
  __shared__ u16 As[128][72];
  __shared__ u16 Bs[128][72];
  int w = threadIdx.x >> 6, ln = threadIdx.x & 63, l15 = ln & 15, q = ln >> 4;
  long rb = (long)blockIdx.y * 128, cb = (long)blockIdx.x * 128;
  int wm = (w >> 1) * 64, wn = (w & 1) * 64;
  f32x4 acc[4][4] = {};
  for (int k0 = 0; k0 < K; k0 += 64) {
    __syncthreads();
    for (int idx = threadIdx.x; idx < 2048; idx += 256) {
      int r = idx >> 4, c4 = (idx & 15) << 2;
      *(uint2*)&As[r][c4] = *(const uint2*)&A[(rb + r) * (long)K + k0 + c4];
      *(uint2*)&Bs[r][c4] = *(const uint2*)&Bt[(cb + r) * (long)K + k0 + c4];
    }
    __syncthreads();
    for (int ks = 0; ks < 2; ks++) {
      bf16x8 af[4], bfr[4];
      for (int mt = 0; mt < 4; mt++)
        af[mt] = *(const bf16x8*)&As[wm + mt * 16 + l15][ks * 32 + q * 8];
      for (int nt = 0; nt < 4; nt++)
        bfr[nt] = *(const bf16x8*)&Bs[wn + nt * 16 + l15][ks * 32 + q * 8];
      for (int mt = 0; mt < 4; mt++)
        for (int nt = 0; nt < 4; nt++)
          acc[mt][nt] = mfma(af[mt], bfr[nt], acc[mt][nt]);
    }
  }
  for (int mt = 0; mt < 4; mt++)
    for (int nt = 0; nt < 4; nt++)
      for (int r = 0; r < 4; r++) {
        long m = rb + wm + mt * 16 + q * 4 + r;
        long n = cb + wn + nt * 16 + l15;
        if (OUT_F32) ((float*)Cout)[m * N + n] = acc[mt][nt][r];
        else ((u16*)Cout)[m * N + n] = f2b(acc[mt][nt][r]);
      }
}

// ---------------- q softmax (per token per head over 128) ----------------
__global__ __launch_bounds__(256) void k_softq(const u16* __restrict__ qkv,
                                               u16* __restrict__ qsb) {
  int job = blockIdx.x * 4 + (threadIdx.x >> 6);
  int ln = threadIdx.x & 63;
  long row = job >> 4; int h = job & 15;
  const u16* src = &qkv[row * 3072 + h * 128];
  float x0 = b2f(src[ln * 2]), x1 = b2f(src[ln * 2 + 1]);
  float mx = fmaxf(x0, x1);
  for (int off = 1; off < 64; off <<= 1) mx = fmaxf(mx, __shfl_xor(mx, off));
  float e0 = __expf(x0 - mx), e1 = __expf(x1 - mx);
  float sm = e0 + e1;
  for (int off = 1; off < 64; off <<= 1) sm += __shfl_xor(sm, off);
  float inv = 1.f / sm;
  u16* dst = &qsb[row * 2048 + h * 128];
  dst[ln * 2] = f2b(e0 * inv);
  dst[ln * 2 + 1] = f2b(e1 * inv);
}

// ---------------- kv prep: ks=softmax(k), beta=exp(logsig(k)/16), kb=ks*beta,
//                  kbT, vT transposed copies ----------------
__global__ __launch_bounds__(256) void k_prepkv(const u16* __restrict__ qkv,
    u16* __restrict__ ksb, u16* __restrict__ kbb, u16* __restrict__ kbT,
    u16* __restrict__ vTb) {
  int job = blockIdx.x * 4 + (threadIdx.x >> 6);
  int ln = threadIdx.x & 63;
  long row = job >> 2; int kv = job & 3;
  int b = (int)(row >> 11), n = (int)(row & 2047);
  const u16* srck = &qkv[row * 3072 + 2048 + kv * 128];
  const u16* srcv = &qkv[row * 3072 + 2560 + kv * 128];
  float k0 = b2f(srck[ln * 2]), k1 = b2f(srck[ln * 2 + 1]);
  float mx = fmaxf(k0, k1);
  for (int off = 1; off < 64; off <<= 1) mx = fmaxf(mx, __shfl_xor(mx, off));
  float e0 = __expf(k0 - mx), e1 = __expf(k1 - mx);
  float sm = e0 + e1;
  for (int off = 1; off < 64; off <<= 1) sm += __shfl_xor(sm, off);
  float inv = 1.f / sm;
  float s0 = e0 * inv, s1 = e1 * inv;
  float bt0 = __expf(logsig(k0) * 0.0625f);
  float bt1 = __expf(logsig(k1) * 0.0625f);
  long o = row * 512 + kv * 128 + ln * 2;
  ksb[o] = f2b(s0); ksb[o + 1] = f2b(s1);
  u16 kb0 = f2b(s0 * bt0), kb1 = f2b(s1 * bt1);
  kbb[o] = kb0; kbb[o + 1] = kb1;
  long c8 = b * 4 + kv;
  kbT[(c8 * 128 + ln * 2) * 2048 + n] = kb0;
  kbT[(c8 * 128 + ln * 2 + 1) * 2048 + n] = kb1;
  vTb[(c8 * 128 + ln * 2) * 2048 + n] = srcv[ln * 2];
  vTb[(c8 * 128 + ln * 2 + 1) * 2048 + n] = srcv[ln * 2 + 1];
}

// ---------------- delta-rule phase 1 (per chunk, C=64) ----------------
// A = strict_tril(Ks Kb^T); T=(I+A)^-1 via nilpotent factorization;
// X = T [Ks|V] -> W (=T K), U0 (=T V); M = I - Kb^T W; NT = U0^T Kb.
__global__ __launch_bounds__(256) void k_phase1(const u16* __restrict__ ksb,
    const u16* __restrict__ kbb, const u16* __restrict__ kbT,
    const u16* __restrict__ qkv, u16* __restrict__ W_g, u16* __restrict__ U0T_g,
    u16* __restrict__ M_g, float* __restrict__ NT_g) {
  __shared__ u16 Pm[64][72];
  __shared__ u16 PT[64][72];
  __shared__ u16 slab[4][64][72];  // XT slabs: slab[s][col][t]
  int cc = blockIdx.x;
  int c8 = cc >> 5, j = cc & 31;
  int b = c8 >> 2, kv = c8 & 3;
  long rb = (long)b * 2048 + j * 64;
  int w = threadIdx.x >> 6, ln = threadIdx.x & 63, l15 = ln & 15, q = ln >> 4;

  // A (negated, strict lower) into Pm/PT
  {
    f32x4 a4[4] = {};
    int m0 = w * 16;
    for (int ks = 0; ks < 4; ks++) {
      bf16x8 af = *(const bf16x8*)&ksb[(rb + m0 + l15) * 512 + kv * 128 + ks * 32 + q * 8];
      for (int nt = 0; nt < 4; nt++) {
        bf16x8 bfr = *(const bf16x8*)&kbb[(rb + nt * 16 + l15) * 512 + kv * 128 + ks * 32 + q * 8];
        a4[nt] = mfma(af, bfr, a4[nt]);
      }
    }
    for (int nt = 0; nt < 4; nt++)
      for (int r = 0; r < 4; r++) {
        int m = m0 + q * 4 + r, n = nt * 16 + l15;
        u16 h = f2b((m > n) ? -a4[nt][r] : 0.f);
        Pm[m][n] = h; PT[n][m] = h;
      }
  }

  // stage initial XT slabs from R = [Ks | V]
  for (int idx = threadIdx.x; idx < 16384; idx += 256) {
    int s = idx >> 12, rem = idx & 4095, t = rem >> 6, c = rem & 63;
    u16 v;
    if (s < 2) v = ksb[(rb + t) * 512 + kv * 128 + s * 64 + c];
    else       v = qkv[(rb + t) * 3072 + 2560 + kv * 128 + (s - 2) * 64 + c];
    slab[s][c][t] = v;
  }
  __syncthreads();

  // X accumulators (wave w owns cols [w*64, w*64+64))
  f32x4 X[4][4];
  for (int mt = 0; mt < 4; mt++)
    for (int nt = 0; nt < 4; nt++)
      for (int r = 0; r < 4; r++)
        X[mt][nt][r] = b2f(slab[w][nt * 16 + l15][mt * 16 + q * 4 + r]);

  for (int f = 0; f < 6; f++) {
    // X += P * X  (first factor: P = -A)
    for (int ks = 0; ks < 2; ks++) {
      bf16x8 af[4], bfr[4];
      for (int mt = 0; mt < 4; mt++)
        af[mt] = *(const bf16x8*)&Pm[mt * 16 + l15][ks * 32 + q * 8];
      for (int nt = 0; nt < 4; nt++)
        bfr[nt] = *(const bf16x8*)&slab[w][nt * 16 + l15][ks * 32 + q * 8];
      for (int mt = 0; mt < 4; mt++)
        for (int nt = 0; nt < 4; nt++)
          X[mt][nt] = mfma(af[mt], bfr[nt], X[mt][nt]);
    }
    // square P
    f32x4 pn[4] = {};
    if (f < 5) {
      int m0 = w * 16;
      for (int ks = 0; ks < 2; ks++) {
        bf16x8 af = *(const bf16x8*)&Pm[m0 + l15][ks * 32 + q * 8];
        for (int nt = 0; nt < 4; nt++) {
          bf16x8 bfr = *(const bf16x8*)&PT[nt * 16 + l15][ks * 32 + q * 8];
          pn[nt] = mfma(af, bfr, pn[nt]);
        }
      }
    }
    __syncthreads();
    for (int mt = 0; mt < 4; mt++)
      for (int nt = 0; nt < 4; nt++)
        for (int r = 0; r < 4; r++)
          slab[w][nt * 16 + l15][mt * 16 + q * 4 + r] = f2b(X[mt][nt][r]);
    if (f < 5) {
      int m0 = w * 16;
      for (int nt = 0; nt < 4; nt++)
        for (int r = 0; r < 4; r++) {
          int m = m0 + q * 4 + r, n = nt * 16 + l15;
          u16 h = f2b(pn[nt][r]);
          Pm[m][n] = h; PT[n][m] = h;
        }
    }
    __syncthreads();
  }

  // W_g [64 t][128 d], U0T_g [128 e][64 t]
  for (int idx = threadIdx.x; idx < 8192; idx += 256) {
    int t = idx >> 7, d = idx & 127;
    W_g[(long)cc * 8192 + idx] = slab[d >> 6][d & 63][t];
  }
  for (int idx = threadIdx.x; idx < 8192; idx += 256) {
    int e = idx >> 6, t = idx & 63;
    U0T_g[(long)cc * 8192 + idx] = slab[2 + (e >> 6)][e & 63][t];
  }

  // M = I - Kb^T W
  {
    f32x4 acc[2][8] = {};
    int m0 = w * 32;
    for (int ks = 0; ks < 2; ks++) {
      bf16x8 af[2], bfr[8];
      for (int mt = 0; mt < 2; mt++)
        af[mt] = *(const bf16x8*)&kbT[((long)(c8 * 128 + m0 + mt * 16 + l15)) * 2048 + j * 64 + ks * 32 + q * 8];
      for (int nt = 0; nt < 8; nt++) {
        int n = nt * 16 + l15;
        bfr[nt] = *(const bf16x8*)&slab[n >> 6][n & 63][ks * 32 + q * 8];
      }
      for (int mt = 0; mt < 2; mt++)
        for (int nt = 0; nt < 8; nt++)
          acc[mt][nt] = mfma(af[mt], bfr[nt], acc[mt][nt]);
    }
    for (int mt = 0; mt < 2; mt++)
      for (int nt = 0; nt < 8; nt++)
        for (int r = 0; r < 4; r++) {
          int i_ = m0 + mt * 16 + q * 4 + r, jj = nt * 16 + l15;
          M_g[(long)cc * 16384 + (long)i_ * 128 + jj] =
              f2b(((i_ == jj) ? 1.f : 0.f) - acc[mt][nt][r]);
        }
  }
  // NT = U0^T Kb
  {
    f32x4 acc[2][8] = {};
    int m0 = w * 32;
    for (int ks = 0; ks < 2; ks++) {
      bf16x8 af[2], bfr[8];
      for (int mt = 0; mt < 2; mt++) {
        int e = m0 + mt * 16 + l15;
        af[mt] = *(const bf16x8*)&slab[2 + (e >> 6)][e & 63][ks * 32 + q * 8];
      }
      for (int nt = 0; nt < 8; nt++)
        bfr[nt] = *(const bf16x8*)&kbT[((long)(c8 * 128 + nt * 16 + l15)) * 2048 + j * 64 + ks * 32 + q * 8];
      for (int mt = 0; mt < 2; mt++)
        for (int nt = 0; nt < 8; nt++)
          acc[mt][nt] = mfma(af[mt], bfr[nt], acc[mt][nt]);
    }
    for (int mt = 0; mt < 2; mt++)
      for (int nt = 0; nt < 8; nt++)
        for (int r = 0; r < 4; r++) {
          int e = m0 + mt * 16 + q * 4 + r, i_ = nt * 16 + l15;
          NT_g[(long)cc * 16384 + (long)e * 128 + i_] = acc[mt][nt][r];
        }
  }
}

// ---------------- phase 2: sequential chunk scan (row-parallel) ----------------
// St' = St * M^T + NT ; emits St0 (chunk-start state, transposed) and UT.
__global__ __launch_bounds__(256) void k_phase2(const u16* __restrict__ W_g,
    const u16* __restrict__ U0T_g, const u16* __restrict__ M_g,
    const float* __restrict__ NT_g, u16* __restrict__ St0_g,
    u16* __restrict__ UT_g) {
  __shared__ u16 St[16][136];
  int c8 = blockIdx.x & 7, eb = blockIdx.x >> 3;
  int e0 = eb * 16;
  int w = threadIdx.x >> 6, ln = threadIdx.x & 63, l15 = ln & 15, q = ln >> 4;
  for (int idx = threadIdx.x; idx < 16 * 128; idx += 256)
    St[idx >> 7][idx & 127] = 0;
  __syncthreads();
  for (int j = 0; j < 32; j++) {
    long cc = c8 * 32 + j;
    for (int idx = threadIdx.x; idx < 2048; idx += 256) {
      int e = idx >> 7, d = idx & 127;
      St0_g[cc * 16384 + (long)(e0 + e) * 128 + d] = St[e][d];
    }
    // UT[e][t] = U0T[e][t] - sum_d St[e][d] W[t][d]
    {
      f32x4 acc = {};
      for (int ks = 0; ks < 4; ks++) {
        bf16x8 af = *(const bf16x8*)&St[l15][ks * 32 + q * 8];
        bf16x8 bfr = *(const bf16x8*)&W_g[cc * 8192 + (long)(w * 16 + l15) * 128 + ks * 32 + q * 8];
        acc = mfma(af, bfr, acc);
      }
      for (int r = 0; r < 4; r++) {
        int e = q * 4 + r, t = w * 16 + l15;
        float v = b2f(U0T_g[cc * 8192 + (long)(e0 + e) * 64 + t]) - acc[r];
        UT_g[cc * 8192 + (long)(e0 + e) * 64 + t] = f2b(v);
      }
    }
    // St' = St * M^T + NT
    f32x4 acc2[2] = {};
    for (int ks = 0; ks < 4; ks++) {
      bf16x8 af = *(const bf16x8*)&St[l15][ks * 32 + q * 8];
      for (int nt = 0; nt < 2; nt++) {
        bf16x8 bfr = *(const bf16x8*)&M_g[cc * 16384 + (long)(w * 32 + nt * 16 + l15) * 128 + ks * 32 + q * 8];
        acc2[nt] = mfma(af, bfr, acc2[nt]);
      }
    }
    for (int nt = 0; nt < 2; nt++)
      for (int r = 0; r < 4; r++)
        acc2[nt][r] += NT_g[cc * 16384 + (long)(e0 + q * 4 + r) * 128 + w * 32 + nt * 16 + l15];
    __syncthreads();
    for (int nt = 0; nt < 2; nt++)
      for (int r = 0; r < 4; r++)
        St[q * 4 + r][w * 32 + nt * 16 + l15] = f2b(acc2[nt][r]);
    __syncthreads();
  }
}

// ---------------- phase 3: per-chunk per-head outputs ----------------
// O = Q*S0 + incl_tril(Q*Kb^T)*U
__global__ __launch_bounds__(256) void k_phase3(const u16* __restrict__ qsb,
    const u16* __restrict__ kbb, const u16* __restrict__ St0_g,
    const u16* __restrict__ UT_g, u16* __restrict__ o_lin) {
  __shared__ u16 Pl[64][72];
  int cc = blockIdx.x >> 2, hh = blockIdx.x & 3;
  int c8 = cc >> 5, j = cc & 31;
  int b = c8 >> 2, kv = c8 & 3, hq = kv * 4 + hh;
  long rb = (long)b * 2048 + j * 64;
  int w = threadIdx.x >> 6, ln = threadIdx.x & 63, l15 = ln & 15, q = ln >> 4;
  int m0 = w * 16;
  f32x4 O[8] = {};
  for (int ks = 0; ks < 4; ks++) {
    bf16x8 af = *(const bf16x8*)&qsb[(rb + m0 + l15) * 2048 + hq * 128 + ks * 32 + q * 8];
    for (int nt = 0; nt < 8; nt++) {
      bf16x8 bfr = *(const bf16x8*)&St0_g[(long)cc * 16384 + (long)(nt * 16 + l15) * 128 + ks * 32 + q * 8];
      O[nt] = mfma(af, bfr, O[nt]);
    }
  }
  {
    f32x4 p4[4] = {};
    for (int ks = 0; ks < 4; ks++) {
      bf16x8 af = *(const bf16x8*)&qsb[(rb + m0 + l15) * 2048 + hq * 128 + ks * 32 + q * 8];
      for (int nt = 0; nt < 4; nt++) {
        bf16x8 bfr = *(const bf16x8*)&kbb[(rb + nt * 16 + l15) * 512 + kv * 128 + ks * 32 + q * 8];
        p4[nt] = mfma(af, bfr, p4[nt]);
      }
    }
    for (int nt = 0; nt < 4; nt++)
      for (int r = 0; r < 4; r++) {
        int m = m0 + q * 4 + r, n = nt * 16 + l15;
        Pl[m][n] = f2b((m >= n) ? p4[nt][r] : 0.f);
      }
  }
  __syncthreads();
  for (int ks = 0; ks < 2; ks++) {
    bf16x8 af = *(const bf16x8*)&Pl[m0 + l15][ks * 32 + q * 8];
    for (int nt = 0; nt < 8; nt++) {
      bf16x8 bfr = *(const bf16x8*)&UT_g[(long)cc * 8192 + (long)(nt * 16 + l15) * 64 + ks * 32 + q * 8];
      O[nt] = mfma(af, bfr, O[nt]);
    }
  }
  for (int nt = 0; nt < 8; nt++)
    for (int r = 0; r < 4; r++) {
      int m = m0 + q * 4 + r, e = nt * 16 + l15;
      o_lin[(rb + m) * 2048 + hq * 128 + e] = f2b(O[nt][r]);
    }
}

// ---------------- flash attention (base branch) + combine ----------------
__global__ __launch_bounds__(256) void k_flash(const u16* __restrict__ qkv,
    const u16* __restrict__ vTb, const u16* __restrict__ o_lin,
    u16* __restrict__ o_comb) {
  __shared__ u16 Pl[128][136];
  int it = blockIdx.x & 15, h = (blockIdx.x >> 4) & 15, b = blockIdx.x >> 8;
  int kv = h >> 2;
  long qb = (long)b * 2048 + it * 128;
  int w = threadIdx.x >> 6, ln = threadIdx.x & 63, l15 = ln & 15, q = ln >> 4;
  int m0 = w * 32;
  const float scale = 0.08838834764831845f;
  f32x4 O[2][8] = {};
  float mrun[2][4], lrun[2][4];
  for (int mt = 0; mt < 2; mt++)
    for (int r = 0; r < 4; r++) { mrun[mt][r] = -3.0e38f; lrun[mt][r] = 0.f; }
  for (int jt = 0; jt <= it; jt++) {
    long kb_ = (long)b * 2048 + jt * 128;
    f32x4 s[2][8] = {};
    for (int ks = 0; ks < 4; ks++) {
      bf16x8 af[2], bfr[8];
      for (int mt = 0; mt < 2; mt++)
        af[mt] = *(const bf16x8*)&qkv[(qb + m0 + mt * 16 + l15) * 3072 + h * 128 + ks * 32 + q * 8];
      for (int nt = 0; nt < 8; nt++)
        bfr[nt] = *(const bf16x8*)&qkv[(kb_ + nt * 16 + l15) * 3072 + 2048 + kv * 128 + ks * 32 + q * 8];
      for (int mt = 0; mt < 2; mt++)
        for (int nt = 0; nt < 8; nt++)
          s[mt][nt] = mfma(af[mt], bfr[nt], s[mt][nt]);
    }
    for (int mt = 0; mt < 2; mt++)
      for (int r = 0; r < 4; r++) {
        int ml = m0 + mt * 16 + q * 4 + r;
        float rmax = -3.0e38f;
        for (int nt = 0; nt < 8; nt++) {
          float v = s[mt][nt][r] * scale;
          if (jt == it && (nt * 16 + l15) > ml) v = -3.0e38f;
          s[mt][nt][r] = v;
          rmax = fmaxf(rmax, v);
        }
        for (int off = 1; off < 16; off <<= 1) rmax = fmaxf(rmax, __shfl_xor(rmax, off));
        float nm = fmaxf(mrun[mt][r], rmax);
        float alpha = __expf(mrun[mt][r] - nm);
        float rsum = 0.f;
        for (int nt = 0; nt < 8; nt++) {
          float p = __expf(s[mt][nt][r] - nm);
          s[mt][nt][r] = p; rsum += p;
        }
        for (int off = 1; off < 16; off <<= 1) rsum += __shfl_xor(rsum, off);
        mrun[mt][r] = nm;
        lrun[mt][r] = lrun[mt][r] * alpha + rsum;
        for (int nt = 0; nt < 8; nt++) O[mt][nt][r] *= alpha;
      }
    for (int mt = 0; mt < 2; mt++)
      for (int nt = 0; nt < 8; nt++)
        for (int r = 0; r < 4; r++)
          Pl[m0 + mt * 16 + q * 4 + r][nt * 16 + l15] = f2b(s[mt][nt][r]);
    __syncthreads();
    for (int ks = 0; ks < 4; ks++) {
      bf16x8 af[2], bfr[8];
      for (int mt = 0; mt < 2; mt++)
        af[mt] = *(const bf16x8*)&Pl[m0 + mt * 16 + l15][ks * 32 + q * 8];
      for (int nt = 0; nt < 8; nt++)
        bfr[nt] = *(const bf16x8*)&vTb[((long)(b * 4 + kv) * 128 + nt * 16 + l15) * 2048 + jt * 128 + ks * 32 + q * 8];
      for (int mt = 0; mt < 2; mt++)
        for (int nt = 0; nt < 8; nt++)
          O[mt][nt] = mfma(af[mt], bfr[nt], O[mt][nt]);
    }
    __syncthreads();
  }
  for (int mt = 0; mt < 2; mt++)
    for (int nt = 0; nt < 8; nt++)
      for (int r = 0; r < 4; r++) {
        int ml = m0 + mt * 16 + q * 4 + r, e = nt * 16 + l15;
        long off = (qb + ml) * 2048 + h * 128 + e;
        float ob = O[mt][nt][r] / lrun[mt][r];
        o_comb[off] = f2b(0.5f * ob + 0.5f * b2f(o_lin[off]));
      }
}

// ---------------- launch ----------------
extern "C" void kernel_launch(void* const* d_in, const int* in_sizes, int n_in,
                              void* d_out, int out_size, void* d_ws, size_t ws_size,
                              hipStream_t stream) {
  const float* hs = (const float*)d_in[0];
  const float* wq = (const float*)d_in[1];
  const float* wk = (const float*)d_in[2];
  const float* wv = (const float*)d_in[3];
  const float* wo = (const float*)d_in[4];

  char* p = (char*)d_ws;
  auto alloc = [&](size_t bytes) {
    char* r = p;
    p += (bytes + 255) & ~(size_t)255;
    return r;
  };
  u16* hsb    = (u16*)alloc(16777216);   // also reused as o_comb
  u16* wqkvT  = (u16*)alloc(12582912);
  u16* woT    = (u16*)alloc(8388608);
  u16* qkv    = (u16*)alloc(25165824);
  u16* qsb    = (u16*)alloc(16777216);
  u16* ksb    = (u16*)alloc(4194304);
  u16* kbb    = (u16*)alloc(4194304);
  u16* kbT    = (u16*)alloc(4194304);
  u16* vTb    = (u16*)alloc(4194304);
  u16* o_lin  = (u16*)alloc(16777216);
  u16* W_g    = (u16*)alloc(4194304);
  u16* U0T_g  = (u16*)alloc(4194304);
  u16* M_g    = (u16*)alloc(8388608);
  float* NT_g = (float*)alloc(16777216);
  u16* St0_g  = (u16*)alloc(8388608);
  u16* UT_g   = (u16*)alloc(4194304);

  k_conv<<<73728, 256, 0, stream>>>(hs, wq, wk, wv, wo, hsb, wqkvT, woT);
  k_gemm<0><<<dim3(24, 32), 256, 0, stream>>>(hsb, wqkvT, qkv, 4096, 3072, 2048);
  k_softq<<<16384, 256, 0, stream>>>(qkv, qsb);
  k_prepkv<<<4096, 256, 0, stream>>>(qkv, ksb, kbb, kbT, vTb);
  k_phase1<<<256, 256, 0, stream>>>(ksb, kbb, kbT, qkv, W_g, U0T_g, M_g, NT_g);
  k_phase2<<<64, 256, 0, stream>>>(W_g, U0T_g, M_g, NT_g, St0_g, UT_g);
  k_phase3<<<1024, 256, 0, stream>>>(qsb, kbb, St0_g, UT_g, o_lin);
  k_flash<<<512, 256, 0, stream>>>(qkv, vTb, o_lin, hsb);
  k_gemm<1><<<dim3(16, 32), 256, 0, stream>>>(hsb, woT, (float*)d_out, 4096, 2048, 2048);
}

// Round 2
// 738.903 us; speedup vs baseline: 1.1756x; 1.1756x over previous
//
#include <hip/hip_runtime.h>

// LiZAttention: gated delta-rule linear attention + causal softmax attention,
// shared QKV / output projections. B=2, N=2048, D=2048, H=16, KVH=4, HD=128.

typedef unsigned short u16;
typedef short bf16x8 __attribute__((ext_vector_type(8)));
typedef float f32x4 __attribute__((ext_vector_type(4)));

#define DEV static __device__ __forceinline__

DEV f32x4 mfma(bf16x8 a, bf16x8 b, f32x4 c) {
  return __builtin_amdgcn_mfma_f32_16x16x32_bf16(a, b, c, 0, 0, 0);
}
DEV u16 f2b(float f) {
  unsigned int u = __builtin_bit_cast(unsigned int, f);
  u = (u + 0x7FFF + ((u >> 16) & 1)) >> 16;
  return (u16)u;
}
DEV float b2f(u16 b) {
  unsigned int u = ((unsigned int)b) << 16;
  return __builtin_bit_cast(float, u);
}
DEV float logsig(float x) { return fminf(x, 0.f) - log1pf(__expf(-fabsf(x))); }

DEV void gll16(const u16* g, u16* l) {
  __builtin_amdgcn_global_load_lds(
      (const __attribute__((address_space(1))) void*)g,
      (__attribute__((address_space(3))) void*)l, 16, 0, 0);
}

// ---------------- conversion / packing ----------------
__global__ __launch_bounds__(256) void k_conv(const float* __restrict__ hs,
    const float* __restrict__ wq, const float* __restrict__ wk,
    const float* __restrict__ wv, const float* __restrict__ wo,
    u16* __restrict__ hsb, u16* __restrict__ wqkvT, u16* __restrict__ woT) {
  long i = (long)blockIdx.x * 256 + threadIdx.x;
  const long NH = 8388608, NW = 6291456, NO = 4194304;
  if (i < NH) { hsb[i] = f2b(hs[i]); return; }
  i -= NH;
  if (i < NW) {
    long n = i >> 11, kk = i & 2047;
    float v = (n < 2048) ? wq[kk * 2048 + n]
            : (n < 2560) ? wk[kk * 512 + (n - 2048)]
                         : wv[kk * 512 + (n - 2560)];
    wqkvT[i] = f2b(v);
    return;
  }
  i -= NW;
  if (i < NO) {
    long n = i >> 11, kk = i & 2047;
    woT[i] = f2b(wo[kk * 2048 + n]);
  }
}

// ---------------- GEMM (m97 structure): C[M][N] = A[M][K] * Bt[N][K]^T --------
template <int OUT_F32>
__global__ __launch_bounds__(256) void k_gemm(const u16* __restrict__ A,
    const u16* __restrict__ Bt, void* __restrict__ Cout, int M, int N, int K) {
  __shared__ u16 As[8192];
  __shared__ u16 Bs[8192];
  int t = threadIdx.x;
  int w = t >> 6, ln = t & 63, l15 = ln & 15, q = ln >> 4;
  long rb = (long)blockIdx.y * 128, cb = (long)blockIdx.x * 128;
  int wm = (w >> 1) * 64, wn = (w & 1) * 64;
  f32x4 acc[4][4] = {};
  int sr = t >> 3, sc = (t & 7) << 3;
  const u16* Ag = &A[(rb + sr) * (long)K + sc];
  const u16* Bg = &Bt[(cb + sr) * (long)K + sc];
  u16* Asl = &As[t * 8];
  u16* Bsl = &Bs[t * 8];
  for (int k0 = 0; k0 < K; k0 += 64) {
    __syncthreads();
    for (int it = 0; it < 4; it++) {
      gll16(Ag + (long)it * 32 * K + k0, Asl + it * 2048);
      gll16(Bg + (long)it * 32 * K + k0, Bsl + it * 2048);
    }
    __syncthreads();
    for (int ks = 0; ks < 2; ks++) {
      bf16x8 af[4], bfr[4];
      for (int mt = 0; mt < 4; mt++)
        af[mt] = *(const bf16x8*)&As[(wm + mt * 16 + l15) * 64 + ks * 32 + q * 8];
      for (int nt = 0; nt < 4; nt++)
        bfr[nt] = *(const bf16x8*)&Bs[(wn + nt * 16 + l15) * 64 + ks * 32 + q * 8];
      for (int mt = 0; mt < 4; mt++)
        for (int nt = 0; nt < 4; nt++)
          acc[mt][nt] = mfma(af[mt], bfr[nt], acc[mt][nt]);
    }
  }
  for (int mt = 0; mt < 4; mt++)
    for (int nt = 0; nt < 4; nt++)
      for (int r = 0; r < 4; r++) {
        long m = rb + wm + mt * 16 + q * 4 + r;
        long n = cb + wn + nt * 16 + l15;
        if (OUT_F32) ((float*)Cout)[m * N + n] = acc[mt][nt][r];
        else ((u16*)Cout)[m * N + n] = f2b(acc[mt][nt][r]);
      }
}

// ---------------- q softmax ----------------
__global__ __launch_bounds__(256) void k_softq(const u16* __restrict__ qkv,
                                               u16* __restrict__ qsb) {
  int job = blockIdx.x * 4 + (threadIdx.x >> 6);
  int ln = threadIdx.x & 63;
  long row = job >> 4; int h = job & 15;
  const u16* src = &qkv[row * 3072 + h * 128];
  float x0 = b2f(src[ln * 2]), x1 = b2f(src[ln * 2 + 1]);
  float mx = fmaxf(x0, x1);
  for (int off = 1; off < 64; off <<= 1) mx = fmaxf(mx, __shfl_xor(mx, off));
  float e0 = __expf(x0 - mx), e1 = __expf(x1 - mx);
  float sm = e0 + e1;
  for (int off = 1; off < 64; off <<= 1) sm += __shfl_xor(sm, off);
  float inv = 1.f / sm;
  u16* dst = &qsb[row * 2048 + h * 128];
  dst[ln * 2] = f2b(e0 * inv);
  dst[ln * 2 + 1] = f2b(e1 * inv);
}

// ---------------- kv prep ----------------
__global__ __launch_bounds__(256) void k_prepkv(const u16* __restrict__ qkv,
    u16* __restrict__ ksb, u16* __restrict__ kbb, u16* __restrict__ kbT,
    u16* __restrict__ vTb) {
  int job = blockIdx.x * 4 + (threadIdx.x >> 6);
  int ln = threadIdx.x & 63;
  long row = job >> 2; int kv = job & 3;
  int b = (int)(row >> 11), n = (int)(row & 2047);
  const u16* srck = &qkv[row * 3072 + 2048 + kv * 128];
  const u16* srcv = &qkv[row * 3072 + 2560 + kv * 128];
  float k0 = b2f(srck[ln * 2]), k1 = b2f(srck[ln * 2 + 1]);
  float mx = fmaxf(k0, k1);
  for (int off = 1; off < 64; off <<= 1) mx = fmaxf(mx, __shfl_xor(mx, off));
  float e0 = __expf(k0 - mx), e1 = __expf(k1 - mx);
  float sm = e0 + e1;
  for (int off = 1; off < 64; off <<= 1) sm += __shfl_xor(sm, off);
  float inv = 1.f / sm;
  float s0 = e0 * inv, s1 = e1 * inv;
  float bt0 = __expf(logsig(k0) * 0.0625f);
  float bt1 = __expf(logsig(k1) * 0.0625f);
  long o = row * 512 + kv * 128 + ln * 2;
  ksb[o] = f2b(s0); ksb[o + 1] = f2b(s1);
  u16 kb0 = f2b(s0 * bt0), kb1 = f2b(s1 * bt1);
  kbb[o] = kb0; kbb[o + 1] = kb1;
  long c8 = b * 4 + kv;
  kbT[(c8 * 128 + ln * 2) * 2048 + n] = kb0;
  kbT[(c8 * 128 + ln * 2 + 1) * 2048 + n] = kb1;
  vTb[(c8 * 128 + ln * 2) * 2048 + n] = srcv[ln * 2];
  vTb[(c8 * 128 + ln * 2 + 1) * 2048 + n] = srcv[ln * 2 + 1];
}

// ---------------- delta-rule phase 1 ----------------
__global__ __launch_bounds__(256) void k_phase1(const u16* __restrict__ ksb,
    const u16* __restrict__ kbb, const u16* __restrict__ kbT,
    const u16* __restrict__ qkv, u16* __restrict__ W_g, u16* __restrict__ U0T_g,
    u16* __restrict__ M_g, float* __restrict__ NT_g) {
  __shared__ u16 Pm[64][72];
  __shared__ u16 PT[64][72];
  __shared__ u16 slab[4][64][72];
  int cc = blockIdx.x;
  int c8 = cc >> 5, j = cc & 31;
  int b = c8 >> 2, kv = c8 & 3;
  long rb = (long)b * 2048 + j * 64;
  int w = threadIdx.x >> 6, ln = threadIdx.x & 63, l15 = ln & 15, q = ln >> 4;
  {
    f32x4 a4[4] = {};
    int m0 = w * 16;
    for (int ks = 0; ks < 4; ks++) {
      bf16x8 af = *(const bf16x8*)&ksb[(rb + m0 + l15) * 512 + kv * 128 + ks * 32 + q * 8];
      for (int nt = 0; nt < 4; nt++) {
        bf16x8 bfr = *(const bf16x8*)&kbb[(rb + nt * 16 + l15) * 512 + kv * 128 + ks * 32 + q * 8];
        a4[nt] = mfma(af, bfr, a4[nt]);
      }
    }
    for (int nt = 0; nt < 4; nt++)
      for (int r = 0; r < 4; r++) {
        int m = m0 + q * 4 + r, n = nt * 16 + l15;
        u16 h = f2b((m > n) ? -a4[nt][r] : 0.f);
        Pm[m][n] = h; PT[n][m] = h;
      }
  }
  for (int idx = threadIdx.x; idx < 16384; idx += 256) {
    int s = idx >> 12, rem = idx & 4095, t = rem >> 6, c = rem & 63;
    u16 v;
    if (s < 2) v = ksb[(rb + t) * 512 + kv * 128 + s * 64 + c];
    else       v = qkv[(rb + t) * 3072 + 2560 + kv * 128 + (s - 2) * 64 + c];
    slab[s][c][t] = v;
  }
  __syncthreads();
  f32x4 X[4][4];
  for (int mt = 0; mt < 4; mt++)
    for (int nt = 0; nt < 4; nt++)
      for (int r = 0; r < 4; r++)
        X[mt][nt][r] = b2f(slab[w][nt * 16 + l15][mt * 16 + q * 4 + r]);
  for (int f = 0; f < 6; f++) {
    for (int ks = 0; ks < 2; ks++) {
      bf16x8 af[4], bfr[4];
      for (int mt = 0; mt < 4; mt++)
        af[mt] = *(const bf16x8*)&Pm[mt * 16 + l15][ks * 32 + q * 8];
      for (int nt = 0; nt < 4; nt++)
        bfr[nt] = *(const bf16x8*)&slab[w][nt * 16 + l15][ks * 32 + q * 8];
      for (int mt = 0; mt < 4; mt++)
        for (int nt = 0; nt < 4; nt++)
          X[mt][nt] = mfma(af[mt], bfr[nt], X[mt][nt]);
    }
    f32x4 pn[4] = {};
    if (f < 5) {
      int m0 = w * 16;
      for (int ks = 0; ks < 2; ks++) {
        bf16x8 af = *(const bf16x8*)&Pm[m0 + l15][ks * 32 + q * 8];
        for (int nt = 0; nt < 4; nt++) {
          bf16x8 bfr = *(const bf16x8*)&PT[nt * 16 + l15][ks * 32 + q * 8];
          pn[nt] = mfma(af, bfr, pn[nt]);
        }
      }
    }
    __syncthreads();
    for (int mt = 0; mt < 4; mt++)
      for (int nt = 0; nt < 4; nt++)
        for (int r = 0; r < 4; r++)
          slab[w][nt * 16 + l15][mt * 16 + q * 4 + r] = f2b(X[mt][nt][r]);
    if (f < 5) {
      int m0 = w * 16;
      for (int nt = 0; nt < 4; nt++)
        for (int r = 0; r < 4; r++) {
          int m = m0 + q * 4 + r, n = nt * 16 + l15;
          u16 h = f2b(pn[nt][r]);
          Pm[m][n] = h; PT[n][m] = h;
        }
    }
    __syncthreads();
  }
  for (int idx = threadIdx.x; idx < 8192; idx += 256) {
    int t = idx >> 7, d = idx & 127;
    W_g[(long)cc * 8192 + idx] = slab[d >> 6][d & 63][t];
  }
  for (int idx = threadIdx.x; idx < 8192; idx += 256) {
    int e = idx >> 6, t = idx & 63;
    U0T_g[(long)cc * 8192 + idx] = slab[2 + (e >> 6)][e & 63][t];
  }
  {
    f32x4 acc[2][8] = {};
    int m0 = w * 32;
    for (int ks = 0; ks < 2; ks++) {
      bf16x8 af[2], bfr[8];
      for (int mt = 0; mt < 2; mt++)
        af[mt] = *(const bf16x8*)&kbT[((long)(c8 * 128 + m0 + mt * 16 + l15)) * 2048 + j * 64 + ks * 32 + q * 8];
      for (int nt = 0; nt < 8; nt++) {
        int n = nt * 16 + l15;
        bfr[nt] = *(const bf16x8*)&slab[n >> 6][n & 63][ks * 32 + q * 8];
      }
      for (int mt = 0; mt < 2; mt++)
        for (int nt = 0; nt < 8; nt++)
          acc[mt][nt] = mfma(af[mt], bfr[nt], acc[mt][nt]);
    }
    for (int mt = 0; mt < 2; mt++)
      for (int nt = 0; nt < 8; nt++)
        for (int r = 0; r < 4; r++) {
          int i_ = m0 + mt * 16 + q * 4 + r, jj = nt * 16 + l15;
          M_g[(long)cc * 16384 + (long)i_ * 128 + jj] =
              f2b(((i_ == jj) ? 1.f : 0.f) - acc[mt][nt][r]);
        }
  }
  {
    f32x4 acc[2][8] = {};
    int m0 = w * 32;
    for (int ks = 0; ks < 2; ks++) {
      bf16x8 af[2], bfr[8];
      for (int mt = 0; mt < 2; mt++) {
        int e = m0 + mt * 16 + l15;
        af[mt] = *(const bf16x8*)&slab[2 + (e >> 6)][e & 63][ks * 32 + q * 8];
      }
      for (int nt = 0; nt < 8; nt++)
        bfr[nt] = *(const bf16x8*)&kbT[((long)(c8 * 128 + nt * 16 + l15)) * 2048 + j * 64 + ks * 32 + q * 8];
      for (int mt = 0; mt < 2; mt++)
        for (int nt = 0; nt < 8; nt++)
          acc[mt][nt] = mfma(af[mt], bfr[nt], acc[mt][nt]);
    }
    for (int mt = 0; mt < 2; mt++)
      for (int nt = 0; nt < 8; nt++)
        for (int r = 0; r < 4; r++) {
          int e = m0 + mt * 16 + q * 4 + r, i_ = nt * 16 + l15;
          NT_g[(long)cc * 16384 + (long)e * 128 + i_] = acc[mt][nt][r];
        }
  }
}

// ---------------- phase 2 ----------------
__global__ __launch_bounds__(256) void k_phase2(const u16* __restrict__ W_g,
    const u16* __restrict__ U0T_g, const u16* __restrict__ M_g,
    const float* __restrict__ NT_g, u16* __restrict__ St0_g,
    u16* __restrict__ UT_g) {
  __shared__ u16 St[16][136];
  int c8 = blockIdx.x & 7, eb = blockIdx.x >> 3;
  int e0 = eb * 16;
  int w = threadIdx.x >> 6, ln = threadIdx.x & 63, l15 = ln & 15, q = ln >> 4;
  for (int idx = threadIdx.x; idx < 16 * 128; idx += 256)
    St[idx >> 7][idx & 127] = 0;
  __syncthreads();
  for (int j = 0; j < 32; j++) {
    long cc = c8 * 32 + j;
    for (int idx = threadIdx.x; idx < 2048; idx += 256) {
      int e = idx >> 7, d = idx & 127;
      St0_g[cc * 16384 + (long)(e0 + e) * 128 + d] = St[e][d];
    }
    {
      f32x4 acc = {};
      for (int ks = 0; ks < 4; ks++) {
        bf16x8 af = *(const bf16x8*)&St[l15][ks * 32 + q * 8];
        bf16x8 bfr = *(const bf16x8*)&W_g[cc * 8192 + (long)(w * 16 + l15) * 128 + ks * 32 + q * 8];
        acc = mfma(af, bfr, acc);
      }
      for (int r = 0; r < 4; r++) {
        int e = q * 4 + r, t = w * 16 + l15;
        float v = b2f(U0T_g[cc * 8192 + (long)(e0 + e) * 64 + t]) - acc[r];
        UT_g[cc * 8192 + (long)(e0 + e) * 64 + t] = f2b(v);
      }
    }
    f32x4 acc2[2] = {};
    for (int ks = 0; ks < 4; ks++) {
      bf16x8 af = *(const bf16x8*)&St[l15][ks * 32 + q * 8];
      for (int nt = 0; nt < 2; nt++) {
        bf16x8 bfr = *(const bf16x8*)&M_g[cc * 16384 + (long)(w * 32 + nt * 16 + l15) * 128 + ks * 32 + q * 8];
        acc2[nt] = mfma(af, bfr, acc2[nt]);
      }
    }
    for (int nt = 0; nt < 2; nt++)
      for (int r = 0; r < 4; r++)
        acc2[nt][r] += NT_g[cc * 16384 + (long)(e0 + q * 4 + r) * 128 + w * 32 + nt * 16 + l15];
    __syncthreads();
    for (int nt = 0; nt < 2; nt++)
      for (int r = 0; r < 4; r++)
        St[q * 4 + r][w * 32 + nt * 16 + l15] = f2b(acc2[nt][r]);
    __syncthreads();
  }
}

// ---------------- phase 3 ----------------
__global__ __launch_bounds__(256) void k_phase3(const u16* __restrict__ qsb,
    const u16* __restrict__ kbb, const u16* __restrict__ St0_g,
    const u16* __restrict__ UT_g, u16* __restrict__ o_lin) {
  __shared__ u16 Pl[64][72];
  int cc = blockIdx.x >> 2, hh = blockIdx.x & 3;
  int c8 = cc >> 5, j = cc & 31;
  int b = c8 >> 2, kv = c8 & 3, hq = kv * 4 + hh;
  long rb = (long)b * 2048 + j * 64;
  int w = threadIdx.x >> 6, ln = threadIdx.x & 63, l15 = ln & 15, q = ln >> 4;
  int m0 = w * 16;
  f32x4 O[8] = {};
  for (int ks = 0; ks < 4; ks++) {
    bf16x8 af = *(const bf16x8*)&qsb[(rb + m0 + l15) * 2048 + hq * 128 + ks * 32 + q * 8];
    for (int nt = 0; nt < 8; nt++) {
      bf16x8 bfr = *(const bf16x8*)&St0_g[(long)cc * 16384 + (long)(nt * 16 + l15) * 128 + ks * 32 + q * 8];
      O[nt] = mfma(af, bfr, O[nt]);
    }
  }
  {
    f32x4 p4[4] = {};
    for (int ks = 0; ks < 4; ks++) {
      bf16x8 af = *(const bf16x8*)&qsb[(rb + m0 + l15) * 2048 + hq * 128 + ks * 32 + q * 8];
      for (int nt = 0; nt < 4; nt++) {
        bf16x8 bfr = *(const bf16x8*)&kbb[(rb + nt * 16 + l15) * 512 + kv * 128 + ks * 32 + q * 8];
        p4[nt] = mfma(af, bfr, p4[nt]);
      }
    }
    for (int nt = 0; nt < 4; nt++)
      for (int r = 0; r < 4; r++) {
        int m = m0 + q * 4 + r, n = nt * 16 + l15;
        Pl[m][n] = f2b((m >= n) ? p4[nt][r] : 0.f);
      }
  }
  __syncthreads();
  for (int ks = 0; ks < 2; ks++) {
    bf16x8 af = *(const bf16x8*)&Pl[m0 + l15][ks * 32 + q * 8];
    for (int nt = 0; nt < 8; nt++) {
      bf16x8 bfr = *(const bf16x8*)&UT_g[(long)cc * 8192 + (long)(nt * 16 + l15) * 64 + ks * 32 + q * 8];
      O[nt] = mfma(af, bfr, O[nt]);
    }
  }
  for (int nt = 0; nt < 8; nt++)
    for (int r = 0; r < 4; r++) {
      int m = m0 + q * 4 + r, e = nt * 16 + l15;
      o_lin[(rb + m) * 2048 + hq * 128 + e] = f2b(O[nt][r]);
    }
}

// ---------------- flash attention (no-max scheme, balanced pairing) ----------
// Each block: q-tiles {p, 31-p} of 64 rows -> exactly 17 kv-tile units.
// S^T = K·Q^T so P lands in per-wave LDS in natural [row][k] layout.
__global__ __launch_bounds__(256) void k_flash(const u16* __restrict__ qkv,
    const u16* __restrict__ vTb, const u16* __restrict__ o_lin,
    u16* __restrict__ o_comb) {
  __shared__ u16 P[4][16][136];
  int p = blockIdx.x & 15, h = (blockIdx.x >> 4) & 15, b = blockIdx.x >> 8;
  int kv = h >> 2;
  int w = threadIdx.x >> 6, ln = threadIdx.x & 63, l15 = ln & 15, q = ln >> 4;
  const float sc2 = 0.127517444f;  // (1/sqrt(128)) * log2(e)
  u16 (*Pw)[136] = P[w];
  const u16* vbase = &vTb[(long)(b * 4 + kv) * 128 * 2048];
  for (int sel = 0; sel < 2; sel++) {
    int qt = sel ? (31 - p) : p;
    long qb = (long)b * 2048 + qt * 64;
    long kvb = (long)b * 2048;
    int njt = (qt >> 1) + 1;
    bf16x8 bq[4];
    for (int ks = 0; ks < 4; ks++)
      bq[ks] = *(const bf16x8*)&qkv[(qb + w * 16 + l15) * 3072 + h * 128 + ks * 32 + q * 8];
    f32x4 O[8] = {};
    float psum = 0.f;
    for (int jt = 0; jt < njt; jt++) {
      long kb = kvb + jt * 128;
      f32x4 st[8] = {};
      for (int ks = 0; ks < 4; ks++)
        for (int mt = 0; mt < 8; mt++) {
          bf16x8 ak = *(const bf16x8*)&qkv[(kb + mt * 16 + l15) * 3072 + 2048 + kv * 128 + ks * 32 + q * 8];
          st[mt] = mfma(ak, bq[ks], st[mt]);
        }
      if (jt == njt - 1) {
        int rg = qt * 64 + w * 16 + l15;
        for (int mt = 0; mt < 8; mt++)
          for (int r = 0; r < 4; r++) {
            int kg = jt * 128 + mt * 16 + q * 4 + r;
            float pv = exp2f(st[mt][r] * sc2);
            pv = (kg > rg) ? 0.f : pv;
            st[mt][r] = pv;
            psum += pv;
          }
      } else {
        for (int mt = 0; mt < 8; mt++)
          for (int r = 0; r < 4; r++) {
            float pv = exp2f(st[mt][r] * sc2);
            st[mt][r] = pv;
            psum += pv;
          }
      }
      // thread holds P^T[k=mt*16+q*4+r][row=l15] -> write P[l15][k], 4 packed
      for (int mt = 0; mt < 8; mt++) {
        u16 pk[4];
        for (int r = 0; r < 4; r++) pk[r] = f2b(st[mt][r]);
        *(uint2*)&Pw[l15][mt * 16 + q * 4] = *(const uint2*)pk;
      }
      for (int ks = 0; ks < 4; ks++) {
        bf16x8 ap = *(const bf16x8*)&Pw[l15][ks * 32 + q * 8];
        for (int nt = 0; nt < 8; nt++) {
          bf16x8 bv = *(const bf16x8*)&vbase[(long)(nt * 16 + l15) * 2048 + jt * 128 + ks * 32 + q * 8];
          O[nt] = mfma(ap, bv, O[nt]);
        }
      }
    }
    psum += __shfl_xor(psum, 16);
    psum += __shfl_xor(psum, 32);
    for (int r = 0; r < 4; r++) {
      float linv = 1.f / __shfl(psum, q * 4 + r);
      int rg = w * 16 + q * 4 + r;
      for (int nt = 0; nt < 8; nt++) {
        long off = (qb + rg) * 2048 + h * 128 + nt * 16 + l15;
        o_comb[off] = f2b(0.5f * O[nt][r] * linv + 0.5f * b2f(o_lin[off]));
      }
    }
  }
}

// ---------------- launch ----------------
extern "C" void kernel_launch(void* const* d_in, const int* in_sizes, int n_in,
                              void* d_out, int out_size, void* d_ws, size_t ws_size,
                              hipStream_t stream) {
  const float* hs = (const float*)d_in[0];
  const float* wq = (const float*)d_in[1];
  const float* wk = (const float*)d_in[2];
  const float* wv = (const float*)d_in[3];
  const float* wo = (const float*)d_in[4];

  char* p = (char*)d_ws;
  auto alloc = [&](size_t bytes) {
    char* r = p;
    p += (bytes + 255) & ~(size_t)255;
    return r;
  };
  u16* hsb    = (u16*)alloc(16777216);   // reused as o_comb
  u16* wqkvT  = (u16*)alloc(12582912);
  u16* woT    = (u16*)alloc(8388608);
  u16* qkv    = (u16*)alloc(25165824);
  u16* qsb    = (u16*)alloc(16777216);
  u16* ksb    = (u16*)alloc(4194304);
  u16* kbb    = (u16*)alloc(4194304);
  u16* kbT    = (u16*)alloc(4194304);
  u16* vTb    = (u16*)alloc(4194304);
  u16* o_lin  = (u16*)alloc(16777216);
  u16* W_g    = (u16*)alloc(4194304);
  u16* U0T_g  = (u16*)alloc(4194304);
  u16* M_g    = (u16*)alloc(8388608);
  float* NT_g = (float*)alloc(16777216);
  u16* St0_g  = (u16*)alloc(8388608);
  u16* UT_g   = (u16*)alloc(4194304);

  k_conv<<<73728, 256, 0, stream>>>(hs, wq, wk, wv, wo, hsb, wqkvT, woT);
  k_gemm<0><<<dim3(24, 32), 256, 0, stream>>>(hsb, wqkvT, qkv, 4096, 3072, 2048);
  k_softq<<<16384, 256, 0, stream>>>(qkv, qsb);
  k_prepkv<<<4096, 256, 0, stream>>>(qkv, ksb, kbb, kbT, vTb);
  k_phase1<<<256, 256, 0, stream>>>(ksb, kbb, kbT, qkv, W_g, U0T_g, M_g, NT_g);
  k_phase2<<<64, 256, 0, stream>>>(W_g, U0T_g, M_g, NT_g, St0_g, UT_g);
  k_phase3<<<1024, 256, 0, stream>>>(qsb, kbb, St0_g, UT_g, o_lin);
  k_flash<<<512, 256, 0, stream>>>(qkv, vTb, o_lin, hsb);
  k_gemm<1><<<dim3(16, 32), 256, 0, stream>>>(hsb, woT, (float*)d_out, 4096, 2048, 2048);
}

// Round 3
// 580.768 us; speedup vs baseline: 1.4956x; 1.2723x over previous
//
#include <hip/hip_runtime.h>

// LiZAttention: gated delta-rule linear attention + causal softmax attention,
// shared QKV / output projections. B=2, N=2048, D=2048, H=16, KVH=4, HD=128.

typedef unsigned short u16;
typedef short bf16x8 __attribute__((ext_vector_type(8)));
typedef float f32x4 __attribute__((ext_vector_type(4)));

#define DEV static __device__ __forceinline__

DEV f32x4 mfma(bf16x8 a, bf16x8 b, f32x4 c) {
  return __builtin_amdgcn_mfma_f32_16x16x32_bf16(a, b, c, 0, 0, 0);
}
DEV u16 f2b(float f) {
  unsigned int u = __builtin_bit_cast(unsigned int, f);
  u = (u + 0x7FFF + ((u >> 16) & 1)) >> 16;
  return (u16)u;
}
DEV float b2f(u16 b) {
  unsigned int u = ((unsigned int)b) << 16;
  return __builtin_bit_cast(float, u);
}
DEV float logsig(float x) { return fminf(x, 0.f) - log1pf(__expf(-fabsf(x))); }

DEV void gll16(const u16* g, u16* l) {
  __builtin_amdgcn_global_load_lds(
      (const __attribute__((address_space(1))) void*)g,
      (__attribute__((address_space(3))) void*)l, 16, 0, 0);
}

// ---------------- prep0: hs cast + tiled weight transposes ----------------
// hsb = bf16(hs); wqkvT[n][k] = bf16([wq|wk|wv][k][n]); woT[n][k] = bf16(wo[k][n])
__global__ __launch_bounds__(256) void k_prep0(const float* __restrict__ hs,
    const float* __restrict__ wq, const float* __restrict__ wk,
    const float* __restrict__ wv, const float* __restrict__ wo,
    u16* __restrict__ hsb, u16* __restrict__ wqkvT, u16* __restrict__ woT) {
  int bid = blockIdx.x;
  int t = threadIdx.x;
  if (bid < 2048) {  // hs cast: 4096 elems/block
    for (int it = 0; it < 4; it++) {
      long i = (long)bid * 4096 + it * 1024 + t * 4;
      const float4 v = *(const float4*)&hs[i];
      u16 o[4] = {f2b(v.x), f2b(v.y), f2b(v.z), f2b(v.w)};
      *(uint2*)&hsb[i] = *(const uint2*)o;
    }
    return;
  }
  bid -= 2048;
  __shared__ u16 T[64][72];  // [k][n]
  const float* s; int sLD; long c0; u16* d; int nb, kb;
  if (bid < 1536) {
    int tn = bid >> 5, tk = bid & 31;
    nb = tn * 64; kb = tk * 64; d = wqkvT;
    if (nb < 2048)      { s = wq; sLD = 2048; c0 = nb; }
    else if (nb < 2560) { s = wk; sLD = 512;  c0 = nb - 2048; }
    else                { s = wv; sLD = 512;  c0 = nb - 2560; }
  } else {
    int b2 = bid - 1536;
    int tn = b2 >> 5, tk = b2 & 31;
    nb = tn * 64; kb = tk * 64; d = woT; s = wo; sLD = 2048; c0 = nb;
  }
  int lr = t >> 4, lc = (t & 15) * 4;
  for (int it = 0; it < 4; it++) {
    int r = lr + it * 16;
    float4 v = *(const float4*)&s[(long)(kb + r) * sLD + c0 + lc];
    u16 o[4] = {f2b(v.x), f2b(v.y), f2b(v.z), f2b(v.w)};
    *(uint2*)&T[r][lc] = *(const uint2*)o;
  }
  __syncthreads();
  int nl = t >> 2, kc = (t & 3) * 16;
  u16 pk[16];
  for (int i = 0; i < 16; i++) pk[i] = T[kc + i][nl];
  u16* dp = &d[(long)(nb + nl) * 2048 + kb + kc];
  *(uint4*)dp = *(const uint4*)pk;
  *(uint4*)(dp + 8) = *(const uint4*)(pk + 8);
}

// ---------------- GEMM (m97 structure): C[M][N] = A[M][K] * Bt[N][K]^T --------
template <int OUT_F32>
__global__ __launch_bounds__(256) void k_gemm(const u16* __restrict__ A,
    const u16* __restrict__ Bt, void* __restrict__ Cout, int M, int N, int K) {
  __shared__ u16 As[8192];
  __shared__ u16 Bs[8192];
  int t = threadIdx.x;
  int w = t >> 6, ln = t & 63, l15 = ln & 15, q = ln >> 4;
  long rb = (long)blockIdx.y * 128, cb = (long)blockIdx.x * 128;
  int wm = (w >> 1) * 64, wn = (w & 1) * 64;
  f32x4 acc[4][4] = {};
  int sr = t >> 3, sc = (t & 7) << 3;
  const u16* Ag = &A[(rb + sr) * (long)K + sc];
  const u16* Bg = &Bt[(cb + sr) * (long)K + sc];
  u16* Asl = &As[t * 8];
  u16* Bsl = &Bs[t * 8];
  for (int k0 = 0; k0 < K; k0 += 64) {
    __syncthreads();
    for (int it = 0; it < 4; it++) {
      gll16(Ag + (long)it * 32 * K + k0, Asl + it * 2048);
      gll16(Bg + (long)it * 32 * K + k0, Bsl + it * 2048);
    }
    __syncthreads();
    for (int ks = 0; ks < 2; ks++) {
      bf16x8 af[4], bfr[4];
      for (int mt = 0; mt < 4; mt++)
        af[mt] = *(const bf16x8*)&As[(wm + mt * 16 + l15) * 64 + ks * 32 + q * 8];
      for (int nt = 0; nt < 4; nt++)
        bfr[nt] = *(const bf16x8*)&Bs[(wn + nt * 16 + l15) * 64 + ks * 32 + q * 8];
      for (int mt = 0; mt < 4; mt++)
        for (int nt = 0; nt < 4; nt++)
          acc[mt][nt] = mfma(af[mt], bfr[nt], acc[mt][nt]);
    }
  }
  for (int mt = 0; mt < 4; mt++)
    for (int nt = 0; nt < 4; nt++)
      for (int r = 0; r < 4; r++) {
        long m = rb + wm + mt * 16 + q * 4 + r;
        long n = cb + wn + nt * 16 + l15;
        if (OUT_F32) ((float*)Cout)[m * N + n] = acc[mt][nt][r];
        else ((u16*)Cout)[m * N + n] = f2b(acc[mt][nt][r]);
      }
}

// ---------------- q softmax ----------------
__global__ __launch_bounds__(256) void k_softq(const u16* __restrict__ qkv,
                                               u16* __restrict__ qsb) {
  int job = blockIdx.x * 4 + (threadIdx.x >> 6);
  int ln = threadIdx.x & 63;
  long row = job >> 4; int h = job & 15;
  const u16* src = &qkv[row * 3072 + h * 128];
  float x0 = b2f(src[ln * 2]), x1 = b2f(src[ln * 2 + 1]);
  float mx = fmaxf(x0, x1);
  for (int off = 1; off < 64; off <<= 1) mx = fmaxf(mx, __shfl_xor(mx, off));
  float e0 = __expf(x0 - mx), e1 = __expf(x1 - mx);
  float sm = e0 + e1;
  for (int off = 1; off < 64; off <<= 1) sm += __shfl_xor(sm, off);
  float inv = 1.f / sm;
  u16* dst = &qsb[row * 2048 + h * 128];
  dst[ln * 2] = f2b(e0 * inv);
  dst[ln * 2 + 1] = f2b(e1 * inv);
}

// ---------------- kv prep: ksb (softmax), kbb (ks*beta) ----------------
__global__ __launch_bounds__(256) void k_prepkv(const u16* __restrict__ qkv,
    u16* __restrict__ ksb, u16* __restrict__ kbb) {
  int job = blockIdx.x * 4 + (threadIdx.x >> 6);
  int ln = threadIdx.x & 63;
  long row = job >> 2; int kv = job & 3;
  const u16* srck = &qkv[row * 3072 + 2048 + kv * 128];
  float k0 = b2f(srck[ln * 2]), k1 = b2f(srck[ln * 2 + 1]);
  float mx = fmaxf(k0, k1);
  for (int off = 1; off < 64; off <<= 1) mx = fmaxf(mx, __shfl_xor(mx, off));
  float e0 = __expf(k0 - mx), e1 = __expf(k1 - mx);
  float sm = e0 + e1;
  for (int off = 1; off < 64; off <<= 1) sm += __shfl_xor(sm, off);
  float inv = 1.f / sm;
  float s0 = e0 * inv, s1 = e1 * inv;
  float bt0 = __expf(logsig(k0) * 0.0625f);
  float bt1 = __expf(logsig(k1) * 0.0625f);
  long o = row * 512 + kv * 128 + ln * 2;
  ksb[o] = f2b(s0); ksb[o + 1] = f2b(s1);
  kbb[o] = f2b(s0 * bt0); kbb[o + 1] = f2b(s1 * bt1);
}

// ---------------- transKV: kbT / vTb tiled transposes ----------------
__global__ __launch_bounds__(256) void k_transKV(const u16* __restrict__ kbb,
    const u16* __restrict__ qkv, u16* __restrict__ kbT, u16* __restrict__ vTb) {
  int bid = blockIdx.x;  // job(2) * c8(8) * dblk(2) * nblk(32)
  int nbk = bid & 31, db = ((bid >> 5) & 1) * 64, c8 = (bid >> 6) & 7, job = bid >> 9;
  int b = c8 >> 2, kv = c8 & 3;
  int nb = nbk * 64;
  __shared__ u16 T[64][72];  // [n][d]
  int t = threadIdx.x;
  int nl = t >> 2, dc = (t & 3) * 16;
  const u16* src; long sLD, soff;
  if (job == 0) { src = kbb; sLD = 512;  soff = kv * 128; }
  else          { src = qkv; sLD = 3072; soff = 2560 + kv * 128; }
  const u16* sp = &src[((long)(b * 2048 + nb + nl)) * sLD + soff + db + dc];
  *(uint4*)&T[nl][dc] = *(const uint4*)sp;
  *(uint4*)&T[nl][dc + 8] = *(const uint4*)(sp + 8);
  __syncthreads();
  int dl = t >> 2, nc = (t & 3) * 16;
  u16 pk[16];
  for (int i = 0; i < 16; i++) pk[i] = T[nc + i][dl];
  u16* d = (job == 0) ? kbT : vTb;
  u16* dp = &d[((long)(c8 * 128 + db + dl)) * 2048 + nb + nc];
  *(uint4*)dp = *(const uint4*)pk;
  *(uint4*)(dp + 8) = *(const uint4*)(pk + 8);
}

// ---------------- delta-rule phase 1 ----------------
__global__ __launch_bounds__(256) void k_phase1(const u16* __restrict__ ksb,
    const u16* __restrict__ kbb, const u16* __restrict__ kbT,
    const u16* __restrict__ qkv, u16* __restrict__ W_g, u16* __restrict__ U0T_g,
    u16* __restrict__ M_g, float* __restrict__ NT_g) {
  __shared__ u16 Pm[64][72];
  __shared__ u16 PT[64][72];
  __shared__ u16 slab[4][64][72];
  int cc = blockIdx.x;
  int c8 = cc >> 5, j = cc & 31;
  int b = c8 >> 2, kv = c8 & 3;
  long rb = (long)b * 2048 + j * 64;
  int w = threadIdx.x >> 6, ln = threadIdx.x & 63, l15 = ln & 15, q = ln >> 4;
  {
    f32x4 a4[4] = {};
    int m0 = w * 16;
    for (int ks = 0; ks < 4; ks++) {
      bf16x8 af = *(const bf16x8*)&ksb[(rb + m0 + l15) * 512 + kv * 128 + ks * 32 + q * 8];
      for (int nt = 0; nt < 4; nt++) {
        bf16x8 bfr = *(const bf16x8*)&kbb[(rb + nt * 16 + l15) * 512 + kv * 128 + ks * 32 + q * 8];
        a4[nt] = mfma(af, bfr, a4[nt]);
      }
    }
    for (int nt = 0; nt < 4; nt++)
      for (int r = 0; r < 4; r++) {
        int m = m0 + q * 4 + r, n = nt * 16 + l15;
        u16 h = f2b((m > n) ? -a4[nt][r] : 0.f);
        Pm[m][n] = h; PT[n][m] = h;
      }
  }
  for (int idx = threadIdx.x; idx < 16384; idx += 256) {
    int s = idx >> 12, rem = idx & 4095, t = rem >> 6, c = rem & 63;
    u16 v;
    if (s < 2) v = ksb[(rb + t) * 512 + kv * 128 + s * 64 + c];
    else       v = qkv[(rb + t) * 3072 + 2560 + kv * 128 + (s - 2) * 64 + c];
    slab[s][c][t] = v;
  }
  __syncthreads();
  f32x4 X[4][4];
  for (int mt = 0; mt < 4; mt++)
    for (int nt = 0; nt < 4; nt++)
      for (int r = 0; r < 4; r++)
        X[mt][nt][r] = b2f(slab[w][nt * 16 + l15][mt * 16 + q * 4 + r]);
  for (int f = 0; f < 6; f++) {
    for (int ks = 0; ks < 2; ks++) {
      bf16x8 af[4], bfr[4];
      for (int mt = 0; mt < 4; mt++)
        af[mt] = *(const bf16x8*)&Pm[mt * 16 + l15][ks * 32 + q * 8];
      for (int nt = 0; nt < 4; nt++)
        bfr[nt] = *(const bf16x8*)&slab[w][nt * 16 + l15][ks * 32 + q * 8];
      for (int mt = 0; mt < 4; mt++)
        for (int nt = 0; nt < 4; nt++)
          X[mt][nt] = mfma(af[mt], bfr[nt], X[mt][nt]);
    }
    f32x4 pn[4] = {};
    if (f < 5) {
      int m0 = w * 16;
      for (int ks = 0; ks < 2; ks++) {
        bf16x8 af = *(const bf16x8*)&Pm[m0 + l15][ks * 32 + q * 8];
        for (int nt = 0; nt < 4; nt++) {
          bf16x8 bfr = *(const bf16x8*)&PT[nt * 16 + l15][ks * 32 + q * 8];
          pn[nt] = mfma(af, bfr, pn[nt]);
        }
      }
    }
    __syncthreads();
    for (int mt = 0; mt < 4; mt++)
      for (int nt = 0; nt < 4; nt++)
        for (int r = 0; r < 4; r++)
          slab[w][nt * 16 + l15][mt * 16 + q * 4 + r] = f2b(X[mt][nt][r]);
    if (f < 5) {
      int m0 = w * 16;
      for (int nt = 0; nt < 4; nt++)
        for (int r = 0; r < 4; r++) {
          int m = m0 + q * 4 + r, n = nt * 16 + l15;
          u16 h = f2b(pn[nt][r]);
          Pm[m][n] = h; PT[n][m] = h;
        }
    }
    __syncthreads();
  }
  for (int idx = threadIdx.x; idx < 8192; idx += 256) {
    int t = idx >> 7, d = idx & 127;
    W_g[(long)cc * 8192 + idx] = slab[d >> 6][d & 63][t];
  }
  for (int idx = threadIdx.x; idx < 8192; idx += 256) {
    int e = idx >> 6, t = idx & 63;
    U0T_g[(long)cc * 8192 + idx] = slab[2 + (e >> 6)][e & 63][t];
  }
  {
    f32x4 acc[2][8] = {};
    int m0 = w * 32;
    for (int ks = 0; ks < 2; ks++) {
      bf16x8 af[2], bfr[8];
      for (int mt = 0; mt < 2; mt++)
        af[mt] = *(const bf16x8*)&kbT[((long)(c8 * 128 + m0 + mt * 16 + l15)) * 2048 + j * 64 + ks * 32 + q * 8];
      for (int nt = 0; nt < 8; nt++) {
        int n = nt * 16 + l15;
        bfr[nt] = *(const bf16x8*)&slab[n >> 6][n & 63][ks * 32 + q * 8];
      }
      for (int mt = 0; mt < 2; mt++)
        for (int nt = 0; nt < 8; nt++)
          acc[mt][nt] = mfma(af[mt], bfr[nt], acc[mt][nt]);
    }
    for (int mt = 0; mt < 2; mt++)
      for (int nt = 0; nt < 8; nt++)
        for (int r = 0; r < 4; r++) {
          int i_ = m0 + mt * 16 + q * 4 + r, jj = nt * 16 + l15;
          M_g[(long)cc * 16384 + (long)i_ * 128 + jj] =
              f2b(((i_ == jj) ? 1.f : 0.f) - acc[mt][nt][r]);
        }
  }
  {
    f32x4 acc[2][8] = {};
    int m0 = w * 32;
    for (int ks = 0; ks < 2; ks++) {
      bf16x8 af[2], bfr[8];
      for (int mt = 0; mt < 2; mt++) {
        int e = m0 + mt * 16 + l15;
        af[mt] = *(const bf16x8*)&slab[2 + (e >> 6)][e & 63][ks * 32 + q * 8];
      }
      for (int nt = 0; nt < 8; nt++)
        bfr[nt] = *(const bf16x8*)&kbT[((long)(c8 * 128 + nt * 16 + l15)) * 2048 + j * 64 + ks * 32 + q * 8];
      for (int mt = 0; mt < 2; mt++)
        for (int nt = 0; nt < 8; nt++)
          acc[mt][nt] = mfma(af[mt], bfr[nt], acc[mt][nt]);
    }
    for (int mt = 0; mt < 2; mt++)
      for (int nt = 0; nt < 8; nt++)
        for (int r = 0; r < 4; r++) {
          int e = m0 + mt * 16 + q * 4 + r, i_ = nt * 16 + l15;
          NT_g[(long)cc * 16384 + (long)e * 128 + i_] = acc[mt][nt][r];
        }
  }
}

// ---------------- phase 2 ----------------
__global__ __launch_bounds__(256) void k_phase2(const u16* __restrict__ W_g,
    const u16* __restrict__ U0T_g, const u16* __restrict__ M_g,
    const float* __restrict__ NT_g, u16* __restrict__ St0_g,
    u16* __restrict__ UT_g) {
  __shared__ u16 St[16][136];
  int c8 = blockIdx.x & 7, eb = blockIdx.x >> 3;
  int e0 = eb * 16;
  int w = threadIdx.x >> 6, ln = threadIdx.x & 63, l15 = ln & 15, q = ln >> 4;
  for (int idx = threadIdx.x; idx < 16 * 128; idx += 256)
    St[idx >> 7][idx & 127] = 0;
  __syncthreads();
  for (int j = 0; j < 32; j++) {
    long cc = c8 * 32 + j;
    for (int idx = threadIdx.x; idx < 2048; idx += 256) {
      int e = idx >> 7, d = idx & 127;
      St0_g[cc * 16384 + (long)(e0 + e) * 128 + d] = St[e][d];
    }
    {
      f32x4 acc = {};
      for (int ks = 0; ks < 4; ks++) {
        bf16x8 af = *(const bf16x8*)&St[l15][ks * 32 + q * 8];
        bf16x8 bfr = *(const bf16x8*)&W_g[cc * 8192 + (long)(w * 16 + l15) * 128 + ks * 32 + q * 8];
        acc = mfma(af, bfr, acc);
      }
      for (int r = 0; r < 4; r++) {
        int e = q * 4 + r, t = w * 16 + l15;
        float v = b2f(U0T_g[cc * 8192 + (long)(e0 + e) * 64 + t]) - acc[r];
        UT_g[cc * 8192 + (long)(e0 + e) * 64 + t] = f2b(v);
      }
    }
    f32x4 acc2[2] = {};
    for (int ks = 0; ks < 4; ks++) {
      bf16x8 af = *(const bf16x8*)&St[l15][ks * 32 + q * 8];
      for (int nt = 0; nt < 2; nt++) {
        bf16x8 bfr = *(const bf16x8*)&M_g[cc * 16384 + (long)(w * 32 + nt * 16 + l15) * 128 + ks * 32 + q * 8];
        acc2[nt] = mfma(af, bfr, acc2[nt]);
      }
    }
    for (int nt = 0; nt < 2; nt++)
      for (int r = 0; r < 4; r++)
        acc2[nt][r] += NT_g[cc * 16384 + (long)(e0 + q * 4 + r) * 128 + w * 32 + nt * 16 + l15];
    __syncthreads();
    for (int nt = 0; nt < 2; nt++)
      for (int r = 0; r < 4; r++)
        St[q * 4 + r][w * 32 + nt * 16 + l15] = f2b(acc2[nt][r]);
    __syncthreads();
  }
}

// ---------------- phase 3 ----------------
__global__ __launch_bounds__(256) void k_phase3(const u16* __restrict__ qsb,
    const u16* __restrict__ kbb, const u16* __restrict__ St0_g,
    const u16* __restrict__ UT_g, u16* __restrict__ o_lin) {
  __shared__ u16 Pl[64][72];
  int cc = blockIdx.x >> 2, hh = blockIdx.x & 3;
  int c8 = cc >> 5, j = cc & 31;
  int b = c8 >> 2, kv = c8 & 3, hq = kv * 4 + hh;
  long rb = (long)b * 2048 + j * 64;
  int w = threadIdx.x >> 6, ln = threadIdx.x & 63, l15 = ln & 15, q = ln >> 4;
  int m0 = w * 16;
  f32x4 O[8] = {};
  for (int ks = 0; ks < 4; ks++) {
    bf16x8 af = *(const bf16x8*)&qsb[(rb + m0 + l15) * 2048 + hq * 128 + ks * 32 + q * 8];
    for (int nt = 0; nt < 8; nt++) {
      bf16x8 bfr = *(const bf16x8*)&St0_g[(long)cc * 16384 + (long)(nt * 16 + l15) * 128 + ks * 32 + q * 8];
      O[nt] = mfma(af, bfr, O[nt]);
    }
  }
  {
    f32x4 p4[4] = {};
    for (int ks = 0; ks < 4; ks++) {
      bf16x8 af = *(const bf16x8*)&qsb[(rb + m0 + l15) * 2048 + hq * 128 + ks * 32 + q * 8];
      for (int nt = 0; nt < 4; nt++) {
        bf16x8 bfr = *(const bf16x8*)&kbb[(rb + nt * 16 + l15) * 512 + kv * 128 + ks * 32 + q * 8];
        p4[nt] = mfma(af, bfr, p4[nt]);
      }
    }
    for (int nt = 0; nt < 4; nt++)
      for (int r = 0; r < 4; r++) {
        int m = m0 + q * 4 + r, n = nt * 16 + l15;
        Pl[m][n] = f2b((m >= n) ? p4[nt][r] : 0.f);
      }
  }
  __syncthreads();
  for (int ks = 0; ks < 2; ks++) {
    bf16x8 af = *(const bf16x8*)&Pl[m0 + l15][ks * 32 + q * 8];
    for (int nt = 0; nt < 8; nt++) {
      bf16x8 bfr = *(const bf16x8*)&UT_g[(long)cc * 8192 + (long)(nt * 16 + l15) * 64 + ks * 32 + q * 8];
      O[nt] = mfma(af, bfr, O[nt]);
    }
  }
  for (int nt = 0; nt < 8; nt++)
    for (int r = 0; r < 4; r++) {
      int m = m0 + q * 4 + r, e = nt * 16 + l15;
      o_lin[(rb + m) * 2048 + hq * 128 + e] = f2b(O[nt][r]);
    }
}

// ---------------- flash attention: 32-row q-tiles, waves split K/V ----------
// Block = (b, h, pair{pr, 63-pr}); uniform 17 KV-tile units; 1024 blocks.
// QK^T: wave w computes S^T rows k in [w*32, w*32+32). PV: wave w computes
// v-cols [w*32, w*32+32). P (32x128) shared via double-buffered LDS.
__global__ __launch_bounds__(256) void k_flash(const u16* __restrict__ qkv,
    const u16* __restrict__ vTb, const u16* __restrict__ o_lin,
    u16* __restrict__ o_comb) {
  __shared__ u16 P[2][32][136];
  __shared__ float psL[4][32];
  int pr = blockIdx.x & 31, h = (blockIdx.x >> 5) & 15, b = blockIdx.x >> 9;
  int kv = h >> 2;
  int w = threadIdx.x >> 6, ln = threadIdx.x & 63, l15 = ln & 15, q = ln >> 4;
  const float sc2 = 0.127517444f;  // (1/sqrt(128)) * log2(e)
  const u16* vb_ = &vTb[((long)(b * 4 + kv) * 128 + w * 32) * 2048];
  long kvb = (long)b * 2048;
  for (int sel = 0; sel < 2; sel++) {
    int qt = sel ? 63 - pr : pr;
    long qb = kvb + qt * 32;
    int njt = (qt >> 2) + 1;
    bf16x8 bq[2][4];
    for (int nt = 0; nt < 2; nt++)
      for (int ks = 0; ks < 4; ks++)
        bq[nt][ks] = *(const bf16x8*)&qkv[(qb + nt * 16 + l15) * 3072 + h * 128 + ks * 32 + q * 8];
    f32x4 O[2][2] = {};
    float psum[2] = {0.f, 0.f};
    for (int jt = 0; jt < njt; jt++) {
      int buf = jt & 1;
      long kb = kvb + jt * 128;
      f32x4 st[2][2] = {};
      for (int ks = 0; ks < 4; ks++) {
        bf16x8 ak0 = *(const bf16x8*)&qkv[(kb + w * 32 + l15) * 3072 + 2048 + kv * 128 + ks * 32 + q * 8];
        bf16x8 ak1 = *(const bf16x8*)&qkv[(kb + w * 32 + 16 + l15) * 3072 + 2048 + kv * 128 + ks * 32 + q * 8];
        for (int nt = 0; nt < 2; nt++) {
          st[0][nt] = mfma(ak0, bq[nt][ks], st[0][nt]);
          st[1][nt] = mfma(ak1, bq[nt][ks], st[1][nt]);
        }
      }
      bool last = (jt == njt - 1);
      for (int mt = 0; mt < 2; mt++)
        for (int nt = 0; nt < 2; nt++) {
          int rg = qt * 32 + nt * 16 + l15;
          for (int r = 0; r < 4; r++) {
            int kg = jt * 128 + w * 32 + mt * 16 + q * 4 + r;
            float pv = exp2f(st[mt][nt][r] * sc2);
            if (last && kg > rg) pv = 0.f;
            st[mt][nt][r] = pv;
            psum[nt] += pv;
          }
        }
      for (int mt = 0; mt < 2; mt++)
        for (int nt = 0; nt < 2; nt++) {
          u16 pk[4];
          for (int r = 0; r < 4; r++) pk[r] = f2b(st[mt][nt][r]);
          *(uint2*)&P[buf][nt * 16 + l15][w * 32 + mt * 16 + q * 4] = *(const uint2*)pk;
        }
      __syncthreads();
      for (int ks = 0; ks < 4; ks++) {
        bf16x8 ap0 = *(const bf16x8*)&P[buf][l15][ks * 32 + q * 8];
        bf16x8 ap1 = *(const bf16x8*)&P[buf][16 + l15][ks * 32 + q * 8];
        bf16x8 bv0 = *(const bf16x8*)&vb_[(long)l15 * 2048 + jt * 128 + ks * 32 + q * 8];
        bf16x8 bv1 = *(const bf16x8*)&vb_[(long)(16 + l15) * 2048 + jt * 128 + ks * 32 + q * 8];
        O[0][0] = mfma(ap0, bv0, O[0][0]);
        O[0][1] = mfma(ap0, bv1, O[0][1]);
        O[1][0] = mfma(ap1, bv0, O[1][0]);
        O[1][1] = mfma(ap1, bv1, O[1][1]);
      }
    }
    for (int nt = 0; nt < 2; nt++) {
      float s = psum[nt];
      s += __shfl_xor(s, 16);
      s += __shfl_xor(s, 32);
      if (q == 0) psL[w][nt * 16 + l15] = s;
    }
    __syncthreads();
    for (int mtp = 0; mtp < 2; mtp++)
      for (int r = 0; r < 4; r++) {
        int row = mtp * 16 + q * 4 + r;
        float tot = psL[0][row] + psL[1][row] + psL[2][row] + psL[3][row];
        float linv = 1.f / tot;
        for (int ntv = 0; ntv < 2; ntv++) {
          long off = (qb + row) * 2048 + h * 128 + w * 32 + ntv * 16 + l15;
          o_comb[off] = f2b(0.5f * O[mtp][ntv][r] * linv + 0.5f * b2f(o_lin[off]));
        }
      }
    __syncthreads();  // protect P/psL reuse across sel
  }
}

// ---------------- launch ----------------
extern "C" void kernel_launch(void* const* d_in, const int* in_sizes, int n_in,
                              void* d_out, int out_size, void* d_ws, size_t ws_size,
                              hipStream_t stream) {
  const float* hs = (const float*)d_in[0];
  const float* wq = (const float*)d_in[1];
  const float* wk = (const float*)d_in[2];
  const float* wv = (const float*)d_in[3];
  const float* wo = (const float*)d_in[4];

  char* p = (char*)d_ws;
  auto alloc = [&](size_t bytes) {
    char* r = p;
    p += (bytes + 255) & ~(size_t)255;
    return r;
  };
  u16* hsb    = (u16*)alloc(16777216);   // reused as o_comb
  u16* wqkvT  = (u16*)alloc(12582912);
  u16* woT    = (u16*)alloc(8388608);
  u16* qkv    = (u16*)alloc(25165824);
  u16* qsb    = (u16*)alloc(16777216);
  u16* ksb    = (u16*)alloc(4194304);
  u16* kbb    = (u16*)alloc(4194304);
  u16* kbT    = (u16*)alloc(4194304);
  u16* vTb    = (u16*)alloc(4194304);
  u16* o_lin  = (u16*)alloc(16777216);
  u16* W_g    = (u16*)alloc(4194304);
  u16* U0T_g  = (u16*)alloc(4194304);
  u16* M_g    = (u16*)alloc(8388608);
  float* NT_g = (float*)alloc(16777216);
  u16* St0_g  = (u16*)alloc(8388608);
  u16* UT_g   = (u16*)alloc(4194304);

  k_prep0<<<4608, 256, 0, stream>>>(hs, wq, wk, wv, wo, hsb, wqkvT, woT);
  k_gemm<0><<<dim3(24, 32), 256, 0, stream>>>(hsb, wqkvT, qkv, 4096, 3072, 2048);
  k_softq<<<16384, 256, 0, stream>>>(qkv, qsb);
  k_prepkv<<<4096, 256, 0, stream>>>(qkv, ksb, kbb);
  k_transKV<<<1024, 256, 0, stream>>>(kbb, qkv, kbT, vTb);
  k_phase1<<<256, 256, 0, stream>>>(ksb, kbb, kbT, qkv, W_g, U0T_g, M_g, NT_g);
  k_phase2<<<64, 256, 0, stream>>>(W_g, U0T_g, M_g, NT_g, St0_g, UT_g);
  k_phase3<<<1024, 256, 0, stream>>>(qsb, kbb, St0_g, UT_g, o_lin);
  k_flash<<<1024, 256, 0, stream>>>(qkv, vTb, o_lin, hsb);
  k_gemm<1><<<dim3(16, 32), 256, 0, stream>>>(hsb, woT, (float*)d_out, 4096, 2048, 2048);
}